// Round 2
// baseline (175.726 us; speedup 1.0000x reference)
//
#include <hip/hip_runtime.h>
#include <stdint.h>

typedef unsigned int u32;
typedef unsigned short u16;
typedef unsigned long long u64;

#define NB 256                      // histogram bins over error in [0,1]
#define NC 20                       // classes
#define K1_BLOCK 256
#define NCTR (NC * NB)              // 5120 packed counters (tot lo16 | fg hi16)
#define DUMP_BYTES (NCTR * 4)       // u32 dump per block = 20480 B
#define FINAL_U32 (NCTR * 2)        // unpacked: tot[5120] then fg[5120]
#define OFF_CE   (FINAL_U32 * 4)    // = 40960
#define OFF_CNT  (OFF_CE + 4)
#define OFF_DUMPS 65536
#define RESERVED  OFF_DUMPS
#define NBLK_K1  1024

// ---------------- kernel 1: softmax + CE + packed privatized histograms ----------------
__global__ __launch_bounds__(K1_BLOCK, 4) void k1_hist(
    const float* __restrict__ logits, const int* __restrict__ tgt, int P,
    u32* __restrict__ dumps, float* __restrict__ ce_sum, u32* __restrict__ valid_cnt)
{
    __shared__ u32 lds[NCTR];            // 20 KiB

    #pragma unroll
    for (int i = threadIdx.x; i < NCTR; i += K1_BLOCK) lds[i] = 0;
    __syncthreads();

    float ce_part = 0.f;
    u32   cnt_part = 0;

    for (long long idx = (long long)blockIdx.x * K1_BLOCK + threadIdx.x; idx < P;
         idx += (long long)NBLK_K1 * K1_BLOCK) {
        const float* row = logits + idx * NC;
        float4 v0 = *(const float4*)(row + 0);
        float4 v1 = *(const float4*)(row + 4);
        float4 v2 = *(const float4*)(row + 8);
        float4 v3 = *(const float4*)(row + 12);
        float4 v4 = *(const float4*)(row + 16);
        float x[NC] = { v0.x, v0.y, v0.z, v0.w,  v1.x, v1.y, v1.z, v1.w,
                        v2.x, v2.y, v2.z, v2.w,  v3.x, v3.y, v3.z, v3.w,
                        v4.x, v4.y, v4.z, v4.w };
        int t = tgt[idx];

        float mx = x[0];
        #pragma unroll
        for (int c = 1; c < NC; ++c) mx = fmaxf(mx, x[c]);

        float e[NC];
        float s = 0.f;
        #pragma unroll
        for (int c = 0; c < NC; ++c) { e[c] = __expf(x[c] - mx); s += e[c]; }
        float inv = 1.0f / s;
        float lse = __logf(s);

        float xt = 0.f;
        #pragma unroll
        for (int c = 0; c < NC; ++c) xt = (c == t) ? x[c] : xt;
        if (t != 0) { ce_part += (mx + lse - xt); cnt_part++; }

        #pragma unroll
        for (int c = 0; c < NC; ++c) {
            float p = e[c] * inv;
            bool is_t = (c == t);
            float err = is_t ? (1.0f - p) : p;
            int b = (int)(err * (float)NB);
            b = b > NB - 1 ? NB - 1 : (b < 0 ? 0 : b);
            atomicAdd(&lds[c * NB + b], is_t ? 0x10001u : 1u);
        }
    }

    // per-wave reduction, direct global atomic (no extra LDS)
    #pragma unroll
    for (int off = 32; off > 0; off >>= 1) {
        ce_part  += __shfl_down(ce_part, off);
        cnt_part += __shfl_down(cnt_part, off);
    }
    if ((threadIdx.x & 63) == 0) {
        atomicAdd(ce_sum, ce_part);
        atomicAdd(valid_cnt, cnt_part);
    }
    __syncthreads();

    // non-atomic per-block dump (u16 halves safe: <=1953 points per block)
    u32* d = dumps + (size_t)blockIdx.x * NCTR;
    #pragma unroll
    for (int i = threadIdx.x; i < NCTR; i += K1_BLOCK) d[i] = lds[i];
}

// ---------------- kernel 2a: reduce + unpack per-block dumps ----------------
__global__ __launch_bounds__(256) void k2a_reduce(
    const u32* __restrict__ dumps, u32* __restrict__ final_hist, int nblk, int chunk)
{
    int counter = (blockIdx.x % 20) * 256 + threadIdx.x;   // 20*256 == 5120
    int part    = blockIdx.x / 20;
    int b0 = part * chunk;
    int b1 = b0 + chunk; if (b1 > nblk) b1 = nblk;
    u32 lo = 0, hi = 0;
    for (int blk = b0; blk < b1; ++blk) {
        u32 v = dumps[(size_t)blk * NCTR + counter];
        lo += v & 0xFFFFu;
        hi += v >> 16;
    }
    if (lo) atomicAdd(&final_hist[counter], lo);           // tot
    if (hi) atomicAdd(&final_hist[NCTR + counter], hi);    // fg
}

// ---------------- kernel 2b: per-class descending bin scan + finalize ----------------
__device__ __forceinline__ float jac_of(float gts, u32 cf, u32 ct)
{
    float I = gts - (float)cf;
    float U = gts + (float)ct - (float)cf;
    return 1.0f - I / U;
}

__global__ __launch_bounds__(256) void k2b_final(
    const u32* __restrict__ final_hist, const float* __restrict__ ce_sum,
    const u32* __restrict__ valid_cnt, float* __restrict__ outp)
{
    __shared__ u64 sc[NB];
    __shared__ float red[NB];
    int t = threadIdx.x;

    float lovsum = 0.f;
    int prescnt = 0;

    for (int c = 0; c < NC; ++c) {
        int b = NB - 1 - t;                 // descending error order
        u32 tot = final_hist[c * NB + b];
        u32 fg  = final_hist[NCTR + c * NB + b];
        u64 v = ((u64)fg << 32) | (u64)tot;

        sc[t] = v;
        __syncthreads();
        for (int off = 1; off < NB; off <<= 1) {
            u64 add = (t >= off) ? sc[t - off] : 0ull;
            __syncthreads();
            sc[t] += add;
            __syncthreads();
        }
        u64 incl  = sc[t];
        u64 total = sc[NB - 1];
        float gts = (float)(u32)(total >> 32);

        float contrib = 0.f;
        if (gts > 0.f) {
            u64 excl = incl - v;
            float jE = jac_of(gts, (u32)(excl >> 32), (u32)excl);
            float jI = jac_of(gts, (u32)(incl >> 32), (u32)incl);
            float eb = ((float)b + 0.5f) * (1.0f / (float)NB);
            contrib = eb * (jI - jE);
        }

        red[t] = contrib;
        __syncthreads();
        #pragma unroll
        for (int off = NB / 2; off > 0; off >>= 1) {
            if (t < off) red[t] += red[t + off];
            __syncthreads();
        }
        if (t == 0 && gts > 0.f) { lovsum += red[0]; prescnt++; }
        __syncthreads();
    }

    if (t == 0) {
        u32 vc = *valid_cnt; if (vc < 1u) vc = 1u;
        float ce = *ce_sum / (float)vc;
        int pc = prescnt < 1 ? 1 : prescnt;
        float lov = lovsum / (float)pc;
        outp[0] = 2.0f * ce;
        outp[1] = 6.0f * lov;
    }
}

// ---------------- launch ----------------
extern "C" void kernel_launch(void* const* d_in, const int* in_sizes, int n_in,
                              void* d_out, int out_size, void* d_ws, size_t ws_size,
                              hipStream_t stream)
{
    const float* logits = (const float*)d_in[0];
    const int*   tgt    = (const int*)d_in[1];
    int P = in_sizes[1];

    char* ws = (char*)d_ws;
    u32*  final_hist = (u32*)ws;
    float* ce_sum    = (float*)(ws + OFF_CE);
    u32*  valid_cnt  = (u32*)(ws + OFF_CNT);
    u32*  dumps      = (u32*)(ws + OFF_DUMPS);

    int nblk = NBLK_K1;
    size_t avail = ws_size > (size_t)RESERVED ? ws_size - RESERVED : 0;
    int maxblk = (int)(avail / DUMP_BYTES);
    if (maxblk < 1) maxblk = 1;
    if (nblk > maxblk) nblk = maxblk;

    hipMemsetAsync(d_ws, 0, RESERVED, stream);
    hipLaunchKernelGGL(k1_hist, dim3(nblk), dim3(K1_BLOCK), 0, stream,
                       logits, tgt, P, dumps, ce_sum, valid_cnt);
    int split = nblk >= 16 ? 16 : 1;
    int chunk = (nblk + split - 1) / split;
    hipLaunchKernelGGL(k2a_reduce, dim3(20 * split), dim3(256), 0, stream,
                       dumps, final_hist, nblk, chunk);
    hipLaunchKernelGGL(k2b_final, dim3(1), dim3(NB), 0, stream,
                       final_hist, ce_sum, valid_cnt, (float*)d_out);
}